// Round 16
// baseline (32.550 us; speedup 1.0000x reference)
//
#include <hip/hip_runtime.h>
#include <math.h>

#define CC 30
#define NBATCH 4096
#define NIJ 49
#define NPAIR 1225            // 49 ij * 25 tail channels (c = 5..29)
#define PSTR 7352             // per-wg partial stride in floats (6*NPAIR=7350, padded to /4)
#define F4TOT (PSTR / 4)
#define THREADS 512
#define SLABF4 1470           // float4 count of a 4-batch slab of one tensor
#define SLABF  5880           // floats per 4-batch slab

// ws layout (NO initialization required — every read location is written first):
//   offset 0      : scal[nwg][4]        (written by yolo_main)
//   offset 8192   : parts2[8][PSTR]     (written by yolo_reduce)
//   offset 243456 : parts[nwg][PSTR]    (written by yolo_main)

__global__ __launch_bounds__(THREADS, 2)   // 2 waves/EU min -> ~256 VGPR budget, no spill
void yolo_main(const float* __restrict__ y, const float* __restrict__ yh,
               float* __restrict__ scal, float* __restrict__ parts, int nwg)
{
    __shared__ __align__(16) float tY[2][SLABF];   // 2 x 23.5 KB
    __shared__ __align__(16) float tH[2][SLABF];   // 2 x 23.5 KB
    __shared__ float scr[4][8];

    const int tid = threadIdx.x;
    const int wg  = blockIdx.x;
    const int bpw = NBATCH / nwg;        // 16 for nwg=256
    const int nslab = bpw >> 2;          // 4  (always a multiple of 4)

    const int i0 = tid, i1 = tid + 512;
    const int i2r = tid + 1024;
    const int i2  = (i2r < SLABF4) ? i2r : (SLABF4 - 1);
    const bool w2 = (i2r < SLABF4);

    int  ijv[3], cv[3], pr[3];
    bool val[3];
    #pragma unroll
    for (int i = 0; i < 3; i++) {
        int p = tid + i * THREADS;
        val[i] = (p < NPAIR);
        pr[i]  = p;
        int pp = val[i] ? p : 0;
        ijv[i] = pp / 25;
        cv[i]  = 5 + pp % 25;
    }

    float D0[3] = {0,0,0}, B0[3] = {0,0,0}, C0[3] = {0,0,0};
    float D1[3] = {0,0,0}, B1[3] = {0,0,0}, C1[3] = {0,0,0};
    float obj = 0.f, noobj = 0.f, coord = 0.f, tt = 0.f;

    const float4* Yg = (const float4*)y;
    const float4* Hg = (const float4*)yh;
    const int sb = wg * (bpw >> 2);      // first slab index of this wg

#define COMPUTE(BUF)                                                            \
    {                                                                           \
        const float* cy = tY[BUF];                                              \
        const float* ch = tH[BUF];                                              \
        if (tid < 4 * NIJ) {                                                    \
            const int base = tid * CC;                                          \
            float y0 = cy[base],     h0 = ch[base];                             \
            float y5 = cy[base + 5], h5 = ch[base + 5];                         \
            float d0 = y0 - h0; d0 *= d0;                                       \
            float d5 = y5 - h5; d5 *= d5;                                       \
            const bool m0 = (y0 == 1.0f), m1 = (y5 == 1.0f);                    \
            obj   += (m0 ? d0 : 0.f) + (m1 ? d5 : 0.f);                         \
            noobj += (m0 ? 0.f : d0) + (m1 ? 0.f : d5);                         \
            if (m0) {                                                           \
                float a  = cy[base + 1] - ch[base + 1];                         \
                float b2 = cy[base + 2] - ch[base + 2];                         \
                float c1 = sqrtf(cy[base + 3]) - sqrtf(ch[base + 3]);           \
                float c2 = sqrtf(cy[base + 4]) - sqrtf(ch[base + 4]);           \
                coord += a * a + b2 * b2 + c1 * c1 + c2 * c2;                   \
            }                                                                   \
            if (m1) {                                                           \
                float a  = cy[base + 6] - ch[base + 6];                         \
                float b2 = cy[base + 7] - ch[base + 7];                         \
                float c1 = sqrtf(cy[base + 8]) - sqrtf(ch[base + 8]);           \
                float c2 = sqrtf(cy[base + 9]) - sqrtf(ch[base + 9]);           \
                coord += a * a + b2 * b2 + c1 * c1 + c2 * c2;                   \
            }                                                                   \
        }                                                                       \
        _Pragma("unroll")                                                       \
        for (int b = 0; b < 4; b++) {                                           \
            _Pragma("unroll")                                                   \
            for (int i = 0; i < 3; i++) {                                       \
                if (!val[i]) continue;                                          \
                const int cb = b * 1470 + ijv[i] * CC;                          \
                const float w0 = (cy[cb] == 1.0f) ? 1.f : 0.f;                  \
                const float wk = (cv[i] >= 10 && cy[cb + 5] == 1.0f) ? 1.f : 0.f;\
                const float t  = cy[cb + cv[i]];                                \
                const float th = ch[cb + cv[i]];                                \
                const float e  = __expf(th);                                    \
                const float te = t * e, ee = e * e, t2 = t * t;                 \
                D0[i] = fmaf(e,  w0, D0[i]);                                    \
                B0[i] = fmaf(te, w0, B0[i]);                                    \
                C0[i] = fmaf(ee, w0, C0[i]);                                    \
                D1[i] = fmaf(e,  wk, D1[i]);                                    \
                B1[i] = fmaf(te, wk, B1[i]);                                    \
                C1[i] = fmaf(ee, wk, C1[i]);                                    \
                tt = fmaf(t2, w0 + wk, tt);                                     \
            }                                                                   \
        }                                                                       \
    }

#define WRITE(BUF, Y0, Y1, Y2, H0, H1, H2)                                      \
    {                                                                           \
        float4* dY = (float4*)tY[BUF];                                          \
        float4* dH = (float4*)tH[BUF];                                          \
        dY[i0] = Y0; dY[i1] = Y1; if (w2) dY[i2] = Y2;                          \
        dH[i0] = H0; dH[i1] = H1; if (w2) dH[i2] = H2;                          \
    }

    for (int ss = 0; ss < nslab; ss += 4) {
        // ---- issue ALL 4 slabs' loads up front: 24 float4 in flight (MLP x4) ----
        const size_t b0 = (size_t)(sb + ss) * SLABF4;
        const size_t b1 = b0 + SLABF4, b2 = b0 + 2 * SLABF4, b3 = b0 + 3 * SLABF4;
        float4 ya0 = Yg[b0+i0], ya1 = Yg[b0+i1], ya2 = Yg[b0+i2];
        float4 ha0 = Hg[b0+i0], ha1 = Hg[b0+i1], ha2 = Hg[b0+i2];
        float4 yb0 = Yg[b1+i0], yb1 = Yg[b1+i1], yb2 = Yg[b1+i2];
        float4 hb0 = Hg[b1+i0], hb1 = Hg[b1+i1], hb2 = Hg[b1+i2];
        float4 yc0 = Yg[b2+i0], yc1 = Yg[b2+i1], yc2 = Yg[b2+i2];
        float4 hc0 = Hg[b2+i0], hc1 = Hg[b2+i1], hc2 = Hg[b2+i2];
        float4 yd0 = Yg[b3+i0], yd1 = Yg[b3+i1], yd2 = Yg[b3+i2];
        float4 hd0 = Hg[b3+i0], hd1 = Hg[b3+i1], hd2 = Hg[b3+i2];

        WRITE(0, ya0, ya1, ya2, ha0, ha1, ha2);
        __syncthreads();

        COMPUTE(0);
        WRITE(1, yb0, yb1, yb2, hb0, hb1, hb2);
        __syncthreads();

        COMPUTE(1);
        WRITE(0, yc0, yc1, yc2, hc0, hc1, hc2);
        __syncthreads();

        COMPUTE(0);
        WRITE(1, yd0, yd1, yd2, hd0, hd1, hd2);
        __syncthreads();

        COMPUTE(1);
        // no barrier needed: next superslab's first write targets buf0, whose
        // readers (COMPUTE at k=2) were fenced two barriers ago
    }
#undef COMPUTE
#undef WRITE

    // ---- per-wg partials: contiguous block, coalesced stores ----
    float* pp = parts + (size_t)wg * PSTR;
    #pragma unroll
    for (int i = 0; i < 3; i++) {
        if (!val[i]) continue;
        const int p = pr[i];
        pp[p]            = D0[i];
        pp[NPAIR + p]    = B0[i];
        pp[2*NPAIR + p]  = C0[i];
        pp[3*NPAIR + p]  = D1[i];   // zero when cv<10
        pp[4*NPAIR + p]  = B1[i];
        pp[5*NPAIR + p]  = C1[i];
    }

    // ---- scalar sums: shuffle -> LDS -> 4 floats per wg ----
    const int lane = tid & 63, wv = tid >> 6;
    #pragma unroll
    for (int off = 32; off > 0; off >>= 1) {
        obj   += __shfl_down(obj,   off);
        noobj += __shfl_down(noobj, off);
        coord += __shfl_down(coord, off);
        tt    += __shfl_down(tt,    off);
    }
    if (lane == 0) { scr[0][wv] = obj; scr[1][wv] = noobj; scr[2][wv] = coord; scr[3][wv] = tt; }
    __syncthreads();
    if (tid < 4) {
        float sacc = 0.f;
        #pragma unroll
        for (int w = 0; w < THREADS / 64; w++) sacc += scr[tid][w];
        scal[wg * 4 + tid] = sacc;
    }
}

// grid (29, 8) x 512: block (bx, cy) sums 64 float4-columns over 1/8 of the wgs
// (8-way sub-split inside the block), float4 loads, LDS fold, plain store.
__global__ __launch_bounds__(512)
void yolo_reduce(const float* __restrict__ parts, float* __restrict__ parts2, int nwg)
{
    const int lane = threadIdx.x & 63;          // float4 column lane
    const int sub  = threadIdx.x >> 6;          // 0..7
    const int f4i  = blockIdx.x * 64 + lane;
    const int cy   = blockIdx.y;                // 0..7
    const int wpc  = nwg >> 3;                  // wgs per chunk (32 for nwg=256)
    const int wps  = wpc >> 3;                  // wgs per sub-group (4)

    float4 s = make_float4(0.f, 0.f, 0.f, 0.f);
    if (f4i < F4TOT) {
        const float* q = parts + (size_t)(cy * wpc + sub * wps) * PSTR + f4i * 4;
        for (int w = 0; w < wps; ++w) {
            float4 a = *(const float4*)q;
            s.x += a.x; s.y += a.y; s.z += a.z; s.w += a.w;
            q += PSTR;
        }
    }
    __shared__ float4 sred[8][64];
    sred[sub][lane] = s;
    __syncthreads();
    if (threadIdx.x < 64 && f4i < F4TOT) {
        float4 t = sred[0][lane];
        #pragma unroll
        for (int c = 1; c < 8; c++) {
            float4 a = sred[c][lane];
            t.x += a.x; t.y += a.y; t.z += a.z; t.w += a.w;
        }
        *(float4*)(parts2 + (size_t)cy * PSTR + f4i * 4) = t;
    }
}

__global__ __launch_bounds__(1024)
void yolo_final(const float* __restrict__ parts2, const float* __restrict__ scal,
                float* __restrict__ out, int nwg)
{
    float v = 0.f;

    for (int s = threadIdx.x; s < NPAIR; s += 1024) {
        const int cidx = s % 25;
        float D0 = 0, B0 = 0, C0 = 0, D1 = 0, B1 = 0, C1 = 0;
        #pragma unroll
        for (int c = 0; c < 8; c++) {
            const float* t = parts2 + (size_t)c * PSTR;
            D0 += t[s];           B0 += t[NPAIR + s];   C0 += t[2*NPAIR + s];
            D1 += t[3*NPAIR + s]; B1 += t[4*NPAIR + s]; C1 += t[5*NPAIR + s];
        }
        if (D0 > 0.f) v += C0 / (D0 * D0) - 2.f * B0 / D0;
        if (cidx >= 5 && D1 > 0.f) v += C1 / (D1 * D1) - 2.f * B1 / D1;
    }

    const float4* s4 = (const float4*)scal;
    for (int w = threadIdx.x; w < nwg; w += 1024) {
        float4 a = s4[w];
        v += a.x + 0.5f * a.y + 5.0f * a.z + a.w;
    }

    __shared__ float sred[16];
    #pragma unroll
    for (int off = 32; off > 0; off >>= 1) v += __shfl_down(v, off);
    const int lane = threadIdx.x & 63, wv = threadIdx.x >> 6;
    if (lane == 0) sred[wv] = v;
    __syncthreads();
    if (threadIdx.x == 0) {
        float tot = 0.f;
        #pragma unroll
        for (int w = 0; w < 16; w++) tot += sred[w];
        out[0] = tot / (float)NBATCH;
    }
}

extern "C" void kernel_launch(void* const* d_in, const int* in_sizes, int n_in,
                              void* d_out, int out_size, void* d_ws, size_t ws_size,
                              hipStream_t stream)
{
    const float* y  = (const float*)d_in[0];
    const float* yh = (const float*)d_in[1];
    float* out    = (float*)d_out;
    float* scal   = (float*)d_ws;
    float* parts2 = (float*)((char*)d_ws + 8192);
    float* parts  = (float*)((char*)d_ws + 243456);

    const size_t per_wg = (size_t)PSTR * sizeof(float);   // 29.4 KB
    int nwg;
    if      (ws_size >= 243456 + 256 * per_wg) nwg = 256;
    else if (ws_size >= 243456 + 128 * per_wg) nwg = 128;
    else                                       nwg = 64;

    yolo_main<<<nwg, THREADS, 0, stream>>>(y, yh, scal, parts, nwg);
    dim3 g2((F4TOT + 63) / 64, 8);
    yolo_reduce<<<g2, 512, 0, stream>>>(parts, parts2, nwg);
    yolo_final<<<1, 1024, 0, stream>>>(parts2, scal, out, nwg);
}

// Round 17
// 29.135 us; speedup vs baseline: 1.1172x; 1.1172x over previous
//
#include <hip/hip_runtime.h>
#include <math.h>

#define CC 30
#define NBATCH 4096
#define NIJ 49
#define NPAIR 1225            // 49 ij * 25 tail channels (c = 5..29)
#define PSTR 7352             // per-wg partial stride in floats (6*NPAIR=7350, padded to /4)
#define F4TOT (PSTR / 4)
#define THREADS 512
#define UNITF4 768            // padded float4 per tensor per 2-batch unit (735 data + 33 pad)
#define UNITF  3072           // floats per tensor per unit

// ws layout (NO initialization required — every read location is written first):
//   offset 0      : scal[nwg][4]        (written by yolo_main)
//   offset 8192   : parts2[8][PSTR]     (written by yolo_reduce)
//   offset 243456 : parts[nwg][PSTR]    (written by yolo_main)

__device__ __forceinline__ void gload_lds16(const void* g, void* l) {
    __builtin_amdgcn_global_load_lds(
        (const __attribute__((address_space(1))) void*)g,
        (__attribute__((address_space(3))) void*)l, 16, 0, 0);
}

__global__ __launch_bounds__(THREADS)
void yolo_main(const float* __restrict__ y, const float* __restrict__ yh,
               float* __restrict__ scal, float* __restrict__ parts, int nwg)
{
    __shared__ __align__(16) float ldsY[4][UNITF];   // 48 KB ring (y)
    __shared__ __align__(16) float ldsH[4][UNITF];   // 48 KB ring (yh)
    __shared__ float scr[4][8];

    const int tid  = threadIdx.x;
    const int wg   = blockIdx.x;
    const int bpw  = NBATCH / nwg;       // 16 for nwg=256
    const int nunit = bpw >> 1;          // 8 two-batch units
    const int wid  = tid >> 6;
    const int lane = tid & 63;
    const int wsub = wid & 3;
    const bool isY = (wid < 4);          // waves 0-3 stage y, 4-7 stage yh

    int  ijv[3], cv[3], pr[3];
    bool val[3];
    #pragma unroll
    for (int i = 0; i < 3; i++) {
        int p = tid + i * THREADS;
        val[i] = (p < NPAIR);
        pr[i]  = p;
        int pp = val[i] ? p : 0;
        ijv[i] = pp / 25;
        cv[i]  = 5 + pp % 25;
    }

    float D0[3] = {0,0,0}, B0[3] = {0,0,0}, C0[3] = {0,0,0};
    float D1[3] = {0,0,0}, B1[3] = {0,0,0}, C1[3] = {0,0,0};
    float obj = 0.f, noobj = 0.f, coord = 0.f, tt = 0.f;

    const float4* gsrc = isY ? (const float4*)y : (const float4*)yh;

    // issue one unit's DMA: 3 x 16B per wave, uniform across all 8 waves.
    // unit uu = 2 batches = 735 float4 of one tensor; pad to 768 absorbs clamp dupes.
#define ISSUE(uu) {                                                             \
        const int    rs_  = (uu) & 3;                                           \
        const size_t bas_ = 735ull * ((size_t)wg * (bpw >> 1) + (uu));          \
        float* ld_ = isY ? ldsY[rs_] : ldsH[rs_];                               \
        _Pragma("unroll")                                                       \
        for (int r_ = 0; r_ < 3; r_++) {                                        \
            const int idx_ = r_ * 256 + wsub * 64 + lane;                       \
            const int src_ = idx_ > 734 ? 734 : idx_;                           \
            gload_lds16(gsrc + bas_ + src_, ld_ + (size_t)idx_ * 4);            \
        } }

    ISSUE(0);
    ISSUE(1);

    for (int u = 0; u < nunit; u++) {
        if (u < nunit - 2) {
            ISSUE(u + 2);
            asm volatile("s_waitcnt vmcnt(6)" ::: "memory");   // unit u landed; u+1,u+2 fly
        } else if (u == nunit - 2) {
            asm volatile("s_waitcnt vmcnt(3)" ::: "memory");
        } else {
            asm volatile("s_waitcnt vmcnt(0)" ::: "memory");
        }
        __builtin_amdgcn_s_barrier();

        const int rs = u & 3;
        const float* cy = ldsY[rs];
        const float* ch = ldsH[rs];

        // ---- pointwise: 98 cells (2 batches) ----
        if (tid < 2 * NIJ) {
            const int base = tid * CC;
            float y0 = cy[base],     h0 = ch[base];
            float y5 = cy[base + 5], h5 = ch[base + 5];
            float d0 = y0 - h0; d0 *= d0;
            float d5 = y5 - h5; d5 *= d5;
            const bool m0 = (y0 == 1.0f), m1 = (y5 == 1.0f);
            obj   += (m0 ? d0 : 0.f) + (m1 ? d5 : 0.f);
            noobj += (m0 ? 0.f : d0) + (m1 ? 0.f : d5);
            if (m0) {
                float a  = cy[base + 1] - ch[base + 1];
                float b2 = cy[base + 2] - ch[base + 2];
                float c1 = sqrtf(cy[base + 3]) - sqrtf(ch[base + 3]);
                float c2 = sqrtf(cy[base + 4]) - sqrtf(ch[base + 4]);
                coord += a * a + b2 * b2 + c1 * c1 + c2 * c2;
            }
            if (m1) {
                float a  = cy[base + 6] - ch[base + 6];
                float b2 = cy[base + 7] - ch[base + 7];
                float c1 = sqrtf(cy[base + 8]) - sqrtf(ch[base + 8]);
                float c2 = sqrtf(cy[base + 9]) - sqrtf(ch[base + 9]);
                coord += a * a + b2 * b2 + c1 * c1 + c2 * c2;
            }
        }

        // ---- slot phase: 2 batches x 3 slots, register accumulation ----
        #pragma unroll
        for (int b = 0; b < 2; b++) {
            #pragma unroll
            for (int i = 0; i < 3; i++) {
                if (!val[i]) continue;
                const int cb = b * 1470 + ijv[i] * CC;
                const float w0 = (cy[cb] == 1.0f) ? 1.f : 0.f;
                const float wk = (cv[i] >= 10 && cy[cb + 5] == 1.0f) ? 1.f : 0.f;
                const float t  = cy[cb + cv[i]];
                const float th = ch[cb + cv[i]];
                const float e  = __expf(th);
                const float te = t * e, ee = e * e, t2 = t * t;
                D0[i] = fmaf(e,  w0, D0[i]);
                B0[i] = fmaf(te, w0, B0[i]);
                C0[i] = fmaf(ee, w0, C0[i]);
                D1[i] = fmaf(e,  wk, D1[i]);
                B1[i] = fmaf(te, wk, B1[i]);
                C1[i] = fmaf(ee, wk, C1[i]);
                tt = fmaf(t2, w0 + wk, tt);
            }
        }
        // no trailing barrier: next iteration's ISSUE targets the ring slot
        // whose readers all finished before the barrier we already passed.
    }
#undef ISSUE

    // ---- per-wg partials: contiguous block, coalesced stores ----
    float* pp = parts + (size_t)wg * PSTR;
    #pragma unroll
    for (int i = 0; i < 3; i++) {
        if (!val[i]) continue;
        const int p = pr[i];
        pp[p]            = D0[i];
        pp[NPAIR + p]    = B0[i];
        pp[2*NPAIR + p]  = C0[i];
        pp[3*NPAIR + p]  = D1[i];   // zero when cv<10
        pp[4*NPAIR + p]  = B1[i];
        pp[5*NPAIR + p]  = C1[i];
    }

    // ---- scalar sums: shuffle -> LDS -> 4 floats per wg ----
    const int wv = wid;
    #pragma unroll
    for (int off = 32; off > 0; off >>= 1) {
        obj   += __shfl_down(obj,   off);
        noobj += __shfl_down(noobj, off);
        coord += __shfl_down(coord, off);
        tt    += __shfl_down(tt,    off);
    }
    if (lane == 0) { scr[0][wv] = obj; scr[1][wv] = noobj; scr[2][wv] = coord; scr[3][wv] = tt; }
    __syncthreads();
    if (tid < 4) {
        float sacc = 0.f;
        #pragma unroll
        for (int w = 0; w < THREADS / 64; w++) sacc += scr[tid][w];
        scal[wg * 4 + tid] = sacc;
    }
}

// grid (29, 8) x 512: block (bx, cy) sums 64 float4-columns over 1/8 of the wgs
// (8-way sub-split inside the block), float4 loads, LDS fold, plain store.
__global__ __launch_bounds__(512)
void yolo_reduce(const float* __restrict__ parts, float* __restrict__ parts2, int nwg)
{
    const int lane = threadIdx.x & 63;          // float4 column lane
    const int sub  = threadIdx.x >> 6;          // 0..7
    const int f4i  = blockIdx.x * 64 + lane;
    const int cy   = blockIdx.y;                // 0..7
    const int wpc  = nwg >> 3;                  // wgs per chunk (32 for nwg=256)
    const int wps  = wpc >> 3;                  // wgs per sub-group (4)

    float4 s = make_float4(0.f, 0.f, 0.f, 0.f);
    if (f4i < F4TOT) {
        const float* q = parts + (size_t)(cy * wpc + sub * wps) * PSTR + f4i * 4;
        for (int w = 0; w < wps; ++w) {
            float4 a = *(const float4*)q;
            s.x += a.x; s.y += a.y; s.z += a.z; s.w += a.w;
            q += PSTR;
        }
    }
    __shared__ float4 sred[8][64];
    sred[sub][lane] = s;
    __syncthreads();
    if (threadIdx.x < 64 && f4i < F4TOT) {
        float4 t = sred[0][lane];
        #pragma unroll
        for (int c = 1; c < 8; c++) {
            float4 a = sred[c][lane];
            t.x += a.x; t.y += a.y; t.z += a.z; t.w += a.w;
        }
        *(float4*)(parts2 + (size_t)cy * PSTR + f4i * 4) = t;
    }
}

__global__ __launch_bounds__(1024)
void yolo_final(const float* __restrict__ parts2, const float* __restrict__ scal,
                float* __restrict__ out, int nwg)
{
    float v = 0.f;

    for (int s = threadIdx.x; s < NPAIR; s += 1024) {
        const int cidx = s % 25;
        float D0 = 0, B0 = 0, C0 = 0, D1 = 0, B1 = 0, C1 = 0;
        #pragma unroll
        for (int c = 0; c < 8; c++) {
            const float* t = parts2 + (size_t)c * PSTR;
            D0 += t[s];           B0 += t[NPAIR + s];   C0 += t[2*NPAIR + s];
            D1 += t[3*NPAIR + s]; B1 += t[4*NPAIR + s]; C1 += t[5*NPAIR + s];
        }
        if (D0 > 0.f) v += C0 / (D0 * D0) - 2.f * B0 / D0;
        if (cidx >= 5 && D1 > 0.f) v += C1 / (D1 * D1) - 2.f * B1 / D1;
    }

    const float4* s4 = (const float4*)scal;
    for (int w = threadIdx.x; w < nwg; w += 1024) {
        float4 a = s4[w];
        v += a.x + 0.5f * a.y + 5.0f * a.z + a.w;
    }

    __shared__ float sred[16];
    #pragma unroll
    for (int off = 32; off > 0; off >>= 1) v += __shfl_down(v, off);
    const int lane = threadIdx.x & 63, wv = threadIdx.x >> 6;
    if (lane == 0) sred[wv] = v;
    __syncthreads();
    if (threadIdx.x == 0) {
        float tot = 0.f;
        #pragma unroll
        for (int w = 0; w < 16; w++) tot += sred[w];
        out[0] = tot / (float)NBATCH;
    }
}

extern "C" void kernel_launch(void* const* d_in, const int* in_sizes, int n_in,
                              void* d_out, int out_size, void* d_ws, size_t ws_size,
                              hipStream_t stream)
{
    const float* y  = (const float*)d_in[0];
    const float* yh = (const float*)d_in[1];
    float* out    = (float*)d_out;
    float* scal   = (float*)d_ws;
    float* parts2 = (float*)((char*)d_ws + 8192);
    float* parts  = (float*)((char*)d_ws + 243456);

    const size_t per_wg = (size_t)PSTR * sizeof(float);   // 29.4 KB
    int nwg;
    if      (ws_size >= 243456 + 256 * per_wg) nwg = 256;
    else if (ws_size >= 243456 + 128 * per_wg) nwg = 128;
    else                                       nwg = 64;

    yolo_main<<<nwg, THREADS, 0, stream>>>(y, yh, scal, parts, nwg);
    dim3 g2((F4TOT + 63) / 64, 8);
    yolo_reduce<<<g2, 512, 0, stream>>>(parts, parts2, nwg);
    yolo_final<<<1, 1024, 0, stream>>>(parts2, scal, out, nwg);
}